// Round 3
// baseline (70.570 us; speedup 1.0000x reference)
//
#include <hip/hip_runtime.h>

// PPO loss fused pipeline for MI355X (gfx950).
// R2: k_mlp restructured to T3 "minimum 2-phase" pipeline: K-step 32,
// double-buffered smA/smB, ONE barrier per K-step, stage(t+1) issued before
// compute(t) so HBM/L2 latency hides under MFMA. New conflict-free swizzle
// (slot ^ ((row>>1)&3)) for 64B rows. gae4 folded into k_mlp (4 launches).

#define TT 65536

typedef float f32x4 __attribute__((ext_vector_type(4)));
typedef __bf16 bf16x8 __attribute__((ext_vector_type(8)));
typedef unsigned short u16x8 __attribute__((ext_vector_type(8)));

__device__ __forceinline__ unsigned short f2bf(float f) {
    unsigned int u = __float_as_uint(f);
    unsigned int r = (u + 0x7fffu + ((u >> 16) & 1u)) >> 16;
    return (unsigned short)r;
}

// branch-free tanh: 1 - 2/(e^{2x}+1)
__device__ __forceinline__ float fast_tanh(float x) {
    float e = __expf(2.0f * x);
    return fmaf(-2.0f, __builtin_amdgcn_rcpf(e + 1.0f), 1.0f);
}

__device__ __forceinline__ void async_lds16(void* lds, const void* g) {
    __builtin_amdgcn_global_load_lds(
        (const __attribute__((address_space(1))) unsigned int*)g,
        (__attribute__((address_space(3))) unsigned int*)lds, 16, 0, 0);
}

// ---------------- GAE affine suffix scan ----------------
__device__ __forceinline__ void suffix_scan256(float* sC, float* sD, int i) {
    float c = sC[i], d = sD[i];
#pragma unroll
    for (int s = 1; s < 256; s <<= 1) {
        float c2 = 1.0f, d2 = 0.0f;
        if (i + s < 256) { c2 = sC[i + s]; d2 = sD[i + s]; }
        __syncthreads();
        d = d + c * d2;
        c = c * c2;
        sC[i] = c; sD[i] = d;
        __syncthreads();
    }
}

__device__ __forceinline__ void gae_cd(const float* rewards, const float* terms,
                                       const float* values, int t, float* c, float* d) {
    float nt = 1.0f - terms[t];
    float nv = (t + 1 < TT) ? values[t + 1] : 0.0f;
    *d = rewards[t] + 0.99f * nv * nt - values[t];
    *c = 0.99f * 0.95f * nt;
}

// ---------------- fused prep + gae1 ----------------
__global__ void k_prep_gae1(const float* __restrict__ W1, const float* __restrict__ W2,
                            const float* __restrict__ Wa, const float* __restrict__ Wc,
                            unsigned short* __restrict__ W1T, unsigned short* __restrict__ W2T,
                            unsigned short* __restrict__ WavT,
                            const float* __restrict__ rewards, const float* __restrict__ terms,
                            const float* __restrict__ values, float* __restrict__ aggC,
                            float* __restrict__ aggD) {
    if (blockIdx.x < 800) {
        int idx = blockIdx.x * 256 + threadIdx.x;
        if (idx < 131072) {
            int n = idx >> 9, k = idx & 511;          // W1T[n][k] = W1[k][n]
            W1T[idx] = f2bf(W1[k * 256 + n]);
        } else if (idx < 196608) {
            int i = idx - 131072;
            int n = i >> 8, k = i & 255;              // W2T[n][k] = W2[k][n]
            W2T[i] = f2bf(W2[k * 256 + n]);
        } else if (idx < 204800) {
            int i = idx - 196608;
            int r = i >> 8, k = i & 255;              // rows 0-15: Wa^T, 16: Wc^T, 17-31: 0
            float v = (r < 16) ? Wa[k * 16 + r] : ((r == 16) ? Wc[k] : 0.0f);
            WavT[i] = f2bf(v);
        }
        return;
    }
    __shared__ float sC[256], sD[256];
    int i = threadIdx.x;
    int b = blockIdx.x - 800;
    int t = b * 256 + i;
    float c, d;
    gae_cd(rewards, terms, values, t, &c, &d);
    sC[i] = c; sD[i] = d;
    __syncthreads();
    suffix_scan256(sC, sD, i);
    if (i == 0) { aggC[b] = sC[0]; aggD[b] = sD[0]; }
}

// ---------------- gae3: carry + adv/ret + per-block sum partials ----------------
__global__ void k_gae3(const float* __restrict__ rewards, const float* __restrict__ terms,
                       const float* __restrict__ values, const float* __restrict__ aggC,
                       const float* __restrict__ aggD, float* __restrict__ adv,
                       float* __restrict__ ret, float* __restrict__ sumP) {
    __shared__ float sC[256], sD[256];
    int i = threadIdx.x, b = blockIdx.x;
    sC[i] = aggC[i]; sD[i] = aggD[i];
    __syncthreads();
    suffix_scan256(sC, sD, i);
    float carry = (b < 255) ? sD[b + 1] : 0.0f;
    __syncthreads();

    int t = b * 256 + i;
    float c, d;
    gae_cd(rewards, terms, values, t, &c, &d);
    sC[i] = c; sD[i] = d;
    __syncthreads();
    suffix_scan256(sC, sD, i);
    float a = sD[i] + sC[i] * carry;
    adv[t] = a;
    ret[t] = a + values[t];
    __syncthreads();
    sC[i] = a; sD[i] = a * a;
    __syncthreads();
#pragma unroll
    for (int s = 128; s > 0; s >>= 1) {
        if (i < s) { sC[i] += sC[i + s]; sD[i] += sD[i + s]; }
        __syncthreads();
    }
    if (i == 0) { sumP[2 * b] = sC[0]; sumP[2 * b + 1] = sD[0]; }
}

// ---------------- fused MLP + heads + loss partials (2-phase pipeline) ----------------
// block = 64 rows, 256 threads (4 waves). Wave w owns output cols [64w,64w+64).
// K-step 32. smA/smB double-buffered; 1 barrier per K-step.
// smA/smB swizzle: 16B slot' = slot ^ ((row>>1)&3)  (rows are 64B).
// smH swizzle: elem' = elem ^ ((row&7)<<3)          (rows are 512B).
__global__ __launch_bounds__(256, 2) void k_mlp(
    const float* __restrict__ obs, const int* __restrict__ actions,
    const float* __restrict__ logprobs, const float* __restrict__ values,
    const float* __restrict__ b1, const float* __restrict__ b2,
    const float* __restrict__ ba, const float* __restrict__ bc,
    const unsigned short* __restrict__ W1T, const unsigned short* __restrict__ W2T,
    const unsigned short* __restrict__ WavT, const float* __restrict__ adv,
    const float* __restrict__ ret, const float* __restrict__ sumP,
    float* __restrict__ lossP) {
    __shared__ __align__(16) unsigned short smA[2][64 * 32];    // 2 x 4KB
    __shared__ __align__(16) unsigned short smB[2][256 * 32];   // 2 x 16KB
    __shared__ __align__(16) unsigned short smH[64 * 256];      // 32KB
    __shared__ float smRed[4];

    const int tid = threadIdx.x;
    const int wid = tid >> 6;
    const int lane = tid & 63;
    const int cl = lane & 15;
    const int gg = lane >> 4;
    const int bm0 = blockIdx.x * 64;

    // ---- inline adv-stats reduction (folds old k_gae4) ----
    float meanA, rstdA;
    {
        float* red = (float*)smH;
        red[tid] = sumP[2 * tid];
        red[256 + tid] = sumP[2 * tid + 1];
        __syncthreads();
#pragma unroll
        for (int s = 128; s > 0; s >>= 1) {
            if (tid < s) { red[tid] += red[tid + s]; red[256 + tid] += red[256 + tid + s]; }
            __syncthreads();
        }
        meanA = red[0] * (1.0f / TT);
        float var = red[256] * (1.0f / TT) - meanA * meanA;
        rstdA = 1.0f / (sqrtf(fmaxf(var, 0.0f)) + 1e-8f);
        __syncthreads();
    }

    float b1v[4], b2v[4];
#pragma unroll
    for (int n = 0; n < 4; ++n) {
        int c = wid * 64 + n * 16 + cl;
        b1v[n] = b1[c];
        b2v[n] = b2[c];
    }
    const float bav = ba[cl];
    const float bc0 = bc[0];

    f32x4 acc[4][4];
#pragma unroll
    for (int m = 0; m < 4; ++m)
#pragma unroll
        for (int n = 0; n < 4; ++n) acc[m][n] = (f32x4){0.f, 0.f, 0.f, 0.f};

    // A addressing: thread covers smA 16B-slot tid -> (row=tid>>2, slot=tid&3)
    const int arow = tid >> 2;
    const int akoff = ((tid & 3) ^ ((arow >> 1) & 3)) << 3;   // elem offset in 32-wide tile
    const float* aptr = obs + (size_t)(bm0 + arow) * 512 + akoff;

    float4 pa[2][2];   // [set][half] — indexed with compile-time constants (full unroll)

    // stage W1T tile t1 (256 rows x 32 k) into smB[t1&1], pre-swizzled source
    auto stageB1 = [&](int t1) {
        const int k0 = t1 * 32;
#pragma unroll
        for (int it = 0; it < 4; ++it) {
            int chunk = it * 4 + wid;
            int row = chunk * 16 + (lane >> 2);
            int koff = ((lane & 3) ^ ((row >> 1) & 3)) << 3;
            async_lds16(&smB[t1 & 1][chunk * 512], W1T + row * 512 + k0 + koff);
        }
    };
    auto stageB2 = [&](int t1) {
        const int k0 = t1 * 32;
#pragma unroll
        for (int it = 0; it < 4; ++it) {
            int chunk = it * 4 + wid;
            int row = chunk * 16 + (lane >> 2);
            int koff = ((lane & 3) ^ ((row >> 1) & 3)) << 3;
            async_lds16(&smB[t1 & 1][chunk * 512], W2T + row * 256 + k0 + koff);
        }
    };
    auto stageWav = [&]() {   // WavT [32][256] -> smB[0] (16KB), smH-style swizzle
#pragma unroll
        for (int it = 0; it < 4; ++it) {
            int chunk = it * 4 + wid;
            int L = chunk * 64 + lane;          // 8-elem slot index 0..1023
            int row = L >> 5;
            int e = (L & 31) * 8;
            async_lds16(&smB[0][chunk * 512], WavT + row * 256 + (e ^ ((row & 7) << 3)));
        }
    };
    auto loadA = [&](int t, float4* dst) {
        dst[0] = *(const float4*)(aptr + t * 32);
        dst[1] = *(const float4*)(aptr + t * 32 + 4);
    };
    auto convA = [&](const float4* src, int buf) {
        u16x8 cc;
        cc[0] = f2bf(src[0].x); cc[1] = f2bf(src[0].y);
        cc[2] = f2bf(src[0].z); cc[3] = f2bf(src[0].w);
        cc[4] = f2bf(src[1].x); cc[5] = f2bf(src[1].y);
        cc[6] = f2bf(src[1].z); cc[7] = f2bf(src[1].w);
        *(u16x8*)&smA[buf][tid * 8] = cc;
    };

    // ---------------- GEMM1: hidden1 = tanh(obs @ W1 + b1), K=512, 16 tiles ----------------
    stageB1(0);
    loadA(0, pa[0]);
    loadA(1, pa[1]);
    convA(pa[0], 0);
    __syncthreads();

#pragma unroll
    for (int t = 0; t < 16; ++t) {
        if (t < 15) stageB1(t + 1); else stageB2(0);   // last iter pre-stages GEMM2 tile 0
        if (t < 14) loadA(t + 2, pa[t & 1]);
        if (t < 15) convA(pa[(t + 1) & 1], (t + 1) & 1);
        bf16x8 av[4], bv[4];
#pragma unroll
        for (int m = 0; m < 4; ++m) {
            int ra = m * 16 + cl;
            av[m] = *(const bf16x8*)&smA[t & 1][ra * 32 + (((gg ^ ((ra >> 1) & 3))) << 3)];
        }
#pragma unroll
        for (int n = 0; n < 4; ++n) {
            int rb = wid * 64 + n * 16 + cl;
            bv[n] = *(const bf16x8*)&smB[t & 1][rb * 32 + (((gg ^ ((rb >> 1) & 3))) << 3)];
        }
#pragma unroll
        for (int m = 0; m < 4; ++m)
#pragma unroll
            for (int n = 0; n < 4; ++n)
                acc[m][n] = __builtin_amdgcn_mfma_f32_16x16x32_bf16(av[m], bv[n], acc[m][n], 0, 0, 0);
        __syncthreads();
    }

    // epilogue 1: tanh + bias -> smH (swizzled), reset acc
#pragma unroll
    for (int m = 0; m < 4; ++m)
#pragma unroll
        for (int n = 0; n < 4; ++n)
#pragma unroll
            for (int j = 0; j < 4; ++j) {
                int r = m * 16 + gg * 4 + j;
                int c = wid * 64 + n * 16 + cl;
                float v = fast_tanh(acc[m][n][j] + b1v[n]);
                smH[r * 256 + (c ^ ((r & 7) << 3))] = f2bf(v);
                acc[m][n][j] = 0.0f;
            }
    __syncthreads();   // smH visible; drains stageB2(0)

    // ---------------- GEMM2: hidden = tanh(hidden1 @ W2 + b2), K=256, 8 tiles ----------------
#pragma unroll
    for (int t = 0; t < 8; ++t) {
        if (t < 7) stageB2(t + 1); else stageWav();    // last iter pre-stages head weights
        bf16x8 av[4], bv[4];
#pragma unroll
        for (int m = 0; m < 4; ++m) {
            int ra = m * 16 + cl;
            av[m] = *(const bf16x8*)&smH[ra * 256 + ((t * 32 + gg * 8) ^ ((ra & 7) << 3))];
        }
#pragma unroll
        for (int n = 0; n < 4; ++n) {
            int rb = wid * 64 + n * 16 + cl;
            bv[n] = *(const bf16x8*)&smB[t & 1][rb * 32 + (((gg ^ ((rb >> 1) & 3))) << 3)];
        }
#pragma unroll
        for (int m = 0; m < 4; ++m)
#pragma unroll
            for (int n = 0; n < 4; ++n)
                acc[m][n] = __builtin_amdgcn_mfma_f32_16x16x32_bf16(av[m], bv[n], acc[m][n], 0, 0, 0);
        __syncthreads();
    }

    // epilogue 2: hidden -> smH
#pragma unroll
    for (int m = 0; m < 4; ++m)
#pragma unroll
        for (int n = 0; n < 4; ++n)
#pragma unroll
            for (int j = 0; j < 4; ++j) {
                int r = m * 16 + gg * 4 + j;
                int c = wid * 64 + n * 16 + cl;
                float v = fast_tanh(acc[m][n][j] + b2v[n]);
                smH[r * 256 + (c ^ ((r & 7) << 3))] = f2bf(v);
            }
    __syncthreads();   // smH + head weights (smB[0]) ready

    // ---------------- heads: logits (A=16) + value ----------------
    f32x4 acc_a = {0.f, 0.f, 0.f, 0.f}, acc_v = {0.f, 0.f, 0.f, 0.f};
#pragma unroll
    for (int kk = 0; kk < 8; ++kk) {
        int r = wid * 16 + cl;
        bf16x8 av = *(const bf16x8*)&smH[r * 256 + ((kk * 32 + gg * 8) ^ ((r & 7) << 3))];
        int ra = cl;
        bf16x8 bva = *(const bf16x8*)&smB[0][ra * 256 + ((kk * 32 + gg * 8) ^ ((ra & 7) << 3))];
        int rv = 16 + cl;
        bf16x8 bvv = *(const bf16x8*)&smB[0][rv * 256 + ((kk * 32 + gg * 8) ^ ((rv & 7) << 3))];
        acc_a = __builtin_amdgcn_mfma_f32_16x16x32_bf16(av, bva, acc_a, 0, 0, 0);
        acc_v = __builtin_amdgcn_mfma_f32_16x16x32_bf16(av, bvv, acc_v, 0, 0, 0);
    }

    // ---------------- per-row softmax + PPO loss ----------------
    float lsum = 0.0f;
    const int t0 = bm0 + wid * 16;
#pragma unroll
    for (int j = 0; j < 4; ++j) {
        int t = t0 + gg * 4 + j;
        float lg = acc_a[j] + bav;
        float mx = lg;
#pragma unroll
        for (int dd = 1; dd < 16; dd <<= 1) mx = fmaxf(mx, __shfl_xor(mx, dd));
        float ex = __expf(lg - mx);
        float se = ex;
#pragma unroll
        for (int dd = 1; dd < 16; dd <<= 1) se += __shfl_xor(se, dd);
        float ls = __logf(se);
        float lp = lg - mx - ls;
        float pl = __expf(lp) * lp;
        float ent = pl;
#pragma unroll
        for (int dd = 1; dd < 16; dd <<= 1) ent += __shfl_xor(ent, dd);
        ent = -ent;
        int act = actions[t];
        float newlp = __shfl(lp, (lane & 48) | act);
        float val = __shfl(acc_v[j], lane & 48) + bc0;

        float lpo = logprobs[t];
        float at = (adv[t] - meanA) * rstdA;
        float rt = ret[t];
        float vo = values[t];
        float ratio = __expf(newlp - lpo);
        float rcl = fminf(fmaxf(ratio, 0.8f), 1.2f);
        float pg = fmaxf(-at * ratio, -at * rcl);
        float vcl = vo + fminf(fmaxf(val - vo, -0.2f), 0.2f);
        float dv = val - rt, dvc = vcl - rt;
        float vl = fmaxf(dv * dv, dvc * dvc);
        if (cl == 0) lsum += pg - 0.01f * ent + 0.25f * vl;
    }
    lsum += __shfl_xor(lsum, 16);
    lsum += __shfl_xor(lsum, 32);
    if (lane == 0) smRed[wid] = lsum;
    __syncthreads();
    if (tid == 0) lossP[blockIdx.x] = smRed[0] + smRed[1] + smRed[2] + smRed[3];
}

__global__ void k_final(const float* __restrict__ lossP, float* __restrict__ out) {
    __shared__ float s[256];
    int i = threadIdx.x;
    s[i] = lossP[i] + lossP[i + 256] + lossP[i + 512] + lossP[i + 768];
    __syncthreads();
#pragma unroll
    for (int st = 128; st > 0; st >>= 1) {
        if (i < st) s[i] += s[i + st];
        __syncthreads();
    }
    if (i == 0) out[0] = s[0] * (1.0f / TT);
}

extern "C" void kernel_launch(void* const* d_in, const int* in_sizes, int n_in,
                              void* d_out, int out_size, void* d_ws, size_t ws_size,
                              hipStream_t stream) {
    const float* obs      = (const float*)d_in[0];
    const int*   actions  = (const int*)d_in[1];
    const float* logprobs = (const float*)d_in[2];
    const float* rewards  = (const float*)d_in[3];
    const float* terms    = (const float*)d_in[4];
    const float* values   = (const float*)d_in[5];
    const float* W1 = (const float*)d_in[6];
    const float* b1 = (const float*)d_in[7];
    const float* W2 = (const float*)d_in[8];
    const float* b2 = (const float*)d_in[9];
    const float* Wa = (const float*)d_in[10];
    const float* ba = (const float*)d_in[11];
    const float* Wc = (const float*)d_in[12];
    const float* bc = (const float*)d_in[13];

    char* ws = (char*)d_ws;
    unsigned short* W1T  = (unsigned short*)(ws + 0);        // 262144 B
    unsigned short* W2T  = (unsigned short*)(ws + 262144);   // 131072 B
    unsigned short* WavT = (unsigned short*)(ws + 393216);   // 16384 B
    float* advp  = (float*)(ws + 409600);                    // 262144 B
    float* retp  = (float*)(ws + 671744);                    // 262144 B
    float* aggC  = (float*)(ws + 933888);                    // 1024 B
    float* aggD  = (float*)(ws + 934912);                    // 1024 B
    float* sumP  = (float*)(ws + 936960);                    // 2048 B
    float* lossP = (float*)(ws + 939072);                    // 4096 B

    k_prep_gae1<<<1056, 256, 0, stream>>>(W1, W2, Wa, Wc, W1T, W2T, WavT,
                                          rewards, terms, values, aggC, aggD);
    k_gae3<<<256, 256, 0, stream>>>(rewards, terms, values, aggC, aggD, advp, retp, sumP);
    k_mlp<<<1024, 256, 0, stream>>>(obs, actions, logprobs, values, b1, b2, ba, bc,
                                    W1T, W2T, WavT, advp, retp, sumP, lossP);
    k_final<<<1, 256, 0, stream>>>(lossP, (float*)d_out);
}